// Round 6
// baseline (276.715 us; speedup 1.0000x reference)
//
#include <hip/hip_runtime.h>
#include <hip/hip_bf16.h>

// B=4, L=2048, DIM=768, H=12, C=64.  M = B*L = 8192.  BH = 48.
// ws (u16 units), SEG = 48*2048*64 = 6291456:
//   Qf32[2S] | K[S] | Vt[S] | Xh[S] (reused as AO after qkv) | Xl[S]
//   | WtH[2304*768] | WtL[2304*768] | Wot[768*768]   ~= 84 MB

typedef unsigned short u16;
typedef u16 u16x2 __attribute__((ext_vector_type(2)));
typedef u16 u16x4 __attribute__((ext_vector_type(4)));
typedef u16 u16x8 __attribute__((ext_vector_type(8)));
typedef short bf16x8 __attribute__((ext_vector_type(8)));
typedef float f32x4 __attribute__((ext_vector_type(4)));

#define MFMA16(acc, a, b) \
  asm("v_mfma_f32_16x16x32_bf16 %0, %1, %2, %0" : "+v"(acc) : "v"(a), "v"(b))

__device__ __forceinline__ u16 f2b(float f) {  // fp32 -> bf16 RNE
  unsigned u = __float_as_uint(f);
  return (u16)((u + 0x7fffu + ((u >> 16) & 1u)) >> 16);
}
__device__ __forceinline__ float b2f(u16 h) {
  return __uint_as_float(((unsigned)h) << 16);
}
__device__ __forceinline__ unsigned pk_bf16(float a, float b) {
  unsigned d;
  asm("v_cvt_pk_bf16_f32 %0, %1, %2" : "=v"(d) : "v"(a), "v"(b));
  return d;  // low16 = bf16(a), high16 = bf16(b)
}

// async global->LDS, 16B per lane. LDS dest must be wave-uniform base.
__device__ __forceinline__ void gload16(const u16* g, u16* l) {
  __builtin_amdgcn_global_load_lds(
      (const __attribute__((address_space(1))) unsigned*)g,
      (__attribute__((address_space(3))) unsigned*)l, 16, 0, 0);
}

// ---------------------------------------------------------------------------
// prep_x: x fp32 [8192][768] -> Xh, Xl bf16 (Dekker hi/lo). 4 elems/thread.
// ---------------------------------------------------------------------------
__global__ __launch_bounds__(256) void prep_x_kernel(
    const float* __restrict__ X, u16* __restrict__ Xh, u16* __restrict__ Xl) {
  const size_t i = ((size_t)blockIdx.x * 256 + threadIdx.x) * 4;
  float4 v = *(const float4*)(X + i);
  u16 h0 = f2b(v.x), h1 = f2b(v.y), h2 = f2b(v.z), h3 = f2b(v.w);
  u16x4 hs = { h0, h1, h2, h3 };
  u16x4 ls = { f2b(v.x - b2f(h0)), f2b(v.y - b2f(h1)),
               f2b(v.z - b2f(h2)), f2b(v.w - b2f(h3)) };
  *(u16x4*)(Xh + i) = hs;
  *(u16x4*)(Xl + i) = ls;
}

// ---------------------------------------------------------------------------
// prep_w: W fp32 [K][N] -> WtH/WtL bf16 [N][K] (transpose + split).
// ---------------------------------------------------------------------------
__global__ __launch_bounds__(256) void prep_w_kernel(
    const float* __restrict__ W, u16* __restrict__ WtH, u16* __restrict__ WtL,
    int K, int N) {
  __shared__ float T[32][33];
  const int k0 = blockIdx.x * 32, n0 = blockIdx.y * 32;
  const int tx = threadIdx.x & 31, ty = threadIdx.x >> 5;
  #pragma unroll
  for (int i = 0; i < 4; ++i)
    T[ty + i * 8][tx] = W[(size_t)(k0 + ty + i * 8) * N + n0 + tx];
  __syncthreads();
  #pragma unroll
  for (int i = 0; i < 4; ++i) {
    const int rn = ty + i * 8, ck = tx;
    float v = T[ck][rn];
    u16 h = f2b(v);
    WtH[(size_t)(n0 + rn) * K + k0 + ck] = h;
    WtL[(size_t)(n0 + rn) * K + k0 + ck] = f2b(v - b2f(h));
  }
}

// prep_wo: Wo fp32 [K][N] -> Wot bf16 [N][K] (transpose, hi only).
__global__ __launch_bounds__(256) void prep_wo_kernel(
    const float* __restrict__ W, u16* __restrict__ Wt, int K, int N) {
  __shared__ float T[32][33];
  const int k0 = blockIdx.x * 32, n0 = blockIdx.y * 32;
  const int tx = threadIdx.x & 31, ty = threadIdx.x >> 5;
  #pragma unroll
  for (int i = 0; i < 4; ++i)
    T[ty + i * 8][tx] = W[(size_t)(k0 + ty + i * 8) * N + n0 + tx];
  __syncthreads();
  #pragma unroll
  for (int i = 0; i < 4; ++i) {
    const int rn = ty + i * 8, ck = tx;
    Wt[(size_t)(n0 + rn) * K + k0 + ck] = f2b(T[ck][rn]);
  }
}

// ---------------------------------------------------------------------------
// Kernel 1: qkv = x @ Wqkv, bf16x3 split (3 MFMAs). 128x128 tile, BK=32,
// 4 waves, global_load_lds width-16 staging, XCD-swizzled block map.
// ---------------------------------------------------------------------------
__global__ __launch_bounds__(256) void qkv_gemm_kernel(
    const u16* __restrict__ Xh, const u16* __restrict__ Xl,
    const u16* __restrict__ WtH, const u16* __restrict__ WtL,
    float* __restrict__ Qo, u16* __restrict__ Ko, u16* __restrict__ Vo) {
  __shared__ u16 Ah[4096], Al[4096], Bh[4096], Bl[4096];  // [128][32] each
  const int tid = threadIdx.x;
  const int w = tid >> 6, l = tid & 63;
  const int llo = l & 15, lhi = l >> 4;
  // XCD swizzle: 1152 blocks, 144 per XCD chunk (bijective, 1152%8==0)
  const int id0 = blockIdx.y * 64 + blockIdx.x;
  const int swz = (id0 & 7) * 144 + (id0 >> 3);
  const int m0 = (swz & 63) * 128, n0 = (swz >> 6) * 128;
  const int wr = (w >> 1) * 64, wc = (w & 1) * 64;

  f32x4 acc[4][4] = {};

  const int sr = tid >> 2;
  const int sc = (tid & 3) * 8;
  const unsigned lb = ((unsigned)w) * 512;
  const u16* axh = Xh + (size_t)(m0 + sr) * 768 + sc;
  const u16* axl = Xl + (size_t)(m0 + sr) * 768 + sc;
  const u16* bwh = WtH + (size_t)(n0 + sr) * 768 + sc;
  const u16* bwl = WtL + (size_t)(n0 + sr) * 768 + sc;
  const size_t half = (size_t)64 * 768;

  for (int k0 = 0; k0 < 768; k0 += 32) {
    __syncthreads();
    gload16(axh + k0,        Ah + lb);
    gload16(axh + half + k0, Ah + 2048 + lb);
    gload16(axl + k0,        Al + lb);
    gload16(axl + half + k0, Al + 2048 + lb);
    gload16(bwh + k0,        Bh + lb);
    gload16(bwh + half + k0, Bh + 2048 + lb);
    gload16(bwl + k0,        Bl + lb);
    gload16(bwl + half + k0, Bl + 2048 + lb);
    __syncthreads();
    bf16x8 ahf[4], alf[4], bhf[4], blf[4];
    #pragma unroll
    for (int i = 0; i < 4; ++i) {
      ahf[i] = *(const bf16x8*)&Ah[(wr + i * 16 + llo) * 32 + lhi * 8];
      alf[i] = *(const bf16x8*)&Al[(wr + i * 16 + llo) * 32 + lhi * 8];
    }
    #pragma unroll
    for (int n = 0; n < 4; ++n) {
      bhf[n] = *(const bf16x8*)&Bh[(wc + n * 16 + llo) * 32 + lhi * 8];
      blf[n] = *(const bf16x8*)&Bl[(wc + n * 16 + llo) * 32 + lhi * 8];
    }
    #pragma unroll
    for (int i = 0; i < 4; ++i)
      #pragma unroll
      for (int n = 0; n < 4; ++n) {
        MFMA16(acc[i][n], ahf[i], bhf[n]);
        MFMA16(acc[i][n], alf[i], bhf[n]);
        MFMA16(acc[i][n], ahf[i], blf[n]);
      }
  }

  const int t = n0 / 768;
  #pragma unroll
  for (int i = 0; i < 4; ++i) {
    #pragma unroll
    for (int n = 0; n < 4; ++n) {
      const int gc = n0 + wc + n * 16 + llo;
      const int rem = gc - t * 768;
      const int h = rem >> 6, c = rem & 63;
      #pragma unroll
      for (int r = 0; r < 4; ++r) {
        const int row = m0 + wr + i * 16 + lhi * 4 + r;
        const int b = row >> 11, lq = row & 2047;
        const size_t bh_ = (size_t)(b * 12 + h);
        const float fv = acc[i][n][r];
        if (t == 0)      Qo[(bh_ * 2048 + lq) * 64 + c] = fv;
        else if (t == 1) Ko[(bh_ * 2048 + lq) * 64 + c] = f2b(fv);
        else             Vo[(bh_ * 64 + c) * 2048 + lq] = f2b(fv);
      }
    }
  }
}

// ---------------------------------------------------------------------------
// Kernel 2: flash attention. 4 waves x 32 q-rows = 128 q/block; each wave's
// K/V fragment reads serve TWO q-sets (halves per-q LDS traffic). Swapped-QK
// in-lane softmax; shfl-free common path (per-lane defer-max test, per-lane
// lsum partial reduced once at end). Single-buffer K/V, T14 async staging.
// ---------------------------------------------------------------------------
__global__ __launch_bounds__(256, 3) void attn_kernel(
    const float* __restrict__ Qf, const u16* __restrict__ Km,
    const u16* __restrict__ Vt, u16* __restrict__ AO) {
  __shared__ u16 Ks[64][72];
  __shared__ u16 Vs[64][72];
  __shared__ u16 Ps[4][32][72];   // [wave][q(2 sets x16)][key]
  const int tid = threadIdx.x;
  const int w = tid >> 6, l = tid & 63;
  const int llo = l & 15, lhi = l >> 4;
  // XCD swizzle: 768 blocks, 96 per XCD -> 6 heads' K/V cluster per XCD L2
  const int id0 = blockIdx.y * 16 + blockIdx.x;
  const int swz = (id0 & 7) * 96 + (id0 >> 3);
  const int bh = swz >> 4;
  const int q0w = (swz & 15) * 128 + w * 32;

  // staging coords: thread covers 32B (16 u16) of each 64x64 tile
  const int kr = tid >> 2, chs = (tid & 3) * 16;
  const u16* Kp = Km + ((size_t)bh * 2048 + kr) * 64 + chs;
  const u16* Vp = Vt + ((size_t)bh * 64 + kr) * 2048 + chs;

  // Q fragments (2 q-sets, hi/lo): lane holds Q[q=llo][c=lhi*8+j]
  bf16x8 qh[2][2], ql[2][2];
  #pragma unroll
  for (int s = 0; s < 2; ++s) {
    const float* Qp = Qf + ((size_t)bh * 2048 + q0w + s * 16 + llo) * 64 + lhi * 8;
    #pragma unroll
    for (int j = 0; j < 8; ++j) {
      float a = Qp[j], b = Qp[32 + j];
      u16 ha = f2b(a), hb = f2b(b);
      qh[s][0][j] = (short)ha; ql[s][0][j] = (short)f2b(a - b2f(ha));
      qh[s][1][j] = (short)hb; ql[s][1][j] = (short)f2b(b - b2f(hb));
    }
  }

  const float L2E = 1.4426950408889634f;
  float mrow[2] = { -1e30f, -1e30f };   // group-uniform (updated on rescale)
  float lsum[2] = { 0.f, 0.f };         // per-lane partial (own 16 keys)
  f32x4 o_acc[2][4] = {};               // [set][cb]: O[q=lhi*4+r][c=cb*16+llo]

  { // prologue: stage tile 0
    u16x8 k0 = *(const u16x8*)(Kp),     k1 = *(const u16x8*)(Kp + 8);
    u16x8 v0 = *(const u16x8*)(Vp),     v1 = *(const u16x8*)(Vp + 8);
    *(u16x8*)&Ks[kr][chs] = k0;  *(u16x8*)&Ks[kr][chs + 8] = k1;
    *(u16x8*)&Vs[kr][chs] = v0;  *(u16x8*)&Vs[kr][chs + 8] = v1;
  }
  __syncthreads();

  for (int kt = 0; kt < 32; ++kt) {
    // T14: issue next-tile loads before compute (vmcnt waits land at ds_write)
    u16x8 nk0, nk1, nv0, nv1;
    if (kt < 31) {
      const u16* kp = Kp + (size_t)(kt + 1) * 4096;
      const u16* vp = Vp + (size_t)(kt + 1) * 64;
      nk0 = *(const u16x8*)(kp);      nk1 = *(const u16x8*)(kp + 8);
      nv0 = *(const u16x8*)(vp);      nv1 = *(const u16x8*)(vp + 8);
    }

    // S^T: s_acc[s][kb4] reg r = S[key=kb4*16+lhi*4+r][q(set s)=llo]
    f32x4 s_acc[2][4] = {};
    #pragma unroll
    for (int kb4 = 0; kb4 < 4; ++kb4) {
      bf16x8 kf0 = *(const bf16x8*)&Ks[kb4 * 16 + llo][lhi * 8];
      bf16x8 kf1 = *(const bf16x8*)&Ks[kb4 * 16 + llo][32 + lhi * 8];
      #pragma unroll
      for (int s = 0; s < 2; ++s) {
        MFMA16(s_acc[s][kb4], kf0, qh[s][0]);
        MFMA16(s_acc[s][kb4], kf0, ql[s][0]);
        MFMA16(s_acc[s][kb4], kf1, qh[s][1]);
        MFMA16(s_acc[s][kb4], kf1, ql[s][1]);
      }
    }

    // per-lane tile max per set (no shfl on common path)
    float tm[2];
    #pragma unroll
    for (int s = 0; s < 2; ++s) {
      float a = fmaxf(fmaxf(s_acc[s][0][0], s_acc[s][0][1]), fmaxf(s_acc[s][0][2], s_acc[s][0][3]));
      float b = fmaxf(fmaxf(s_acc[s][1][0], s_acc[s][1][1]), fmaxf(s_acc[s][1][2], s_acc[s][1][3]));
      float c = fmaxf(fmaxf(s_acc[s][2][0], s_acc[s][2][1]), fmaxf(s_acc[s][2][2], s_acc[s][2][3]));
      float d = fmaxf(fmaxf(s_acc[s][3][0], s_acc[s][3][1]), fmaxf(s_acc[s][3][2], s_acc[s][3][3]));
      tm[s] = fmaxf(fmaxf(a, b), fmaxf(c, d));
    }

    // defer-max: rescale (rare) when any lane's partial max grew past THR=8
    if (!__all(tm[0] <= mrow[0] + 8.f && tm[1] <= mrow[1] + 8.f)) {
      #pragma unroll
      for (int s = 0; s < 2; ++s) {
        float g = tm[s];
        g = fmaxf(g, __shfl_xor(g, 16));
        g = fmaxf(g, __shfl_xor(g, 32));
        const float mn = fmaxf(mrow[s], g);
        const float scale = __expf(mrow[s] - mn);
        mrow[s] = mn;
        lsum[s] *= scale;
        float scr[4];
        #pragma unroll
        for (int r = 0; r < 4; ++r) scr[r] = __shfl(scale, lhi * 20 + r);
        #pragma unroll
        for (int cb = 0; cb < 4; ++cb)
          #pragma unroll
          for (int r = 0; r < 4; ++r) o_acc[s][cb][r] *= scr[r];
      }
    }

    // P = exp(S - mrow), packed bf16 stores; lsum accumulates per-lane
    #pragma unroll
    for (int s = 0; s < 2; ++s) {
      const float mb = mrow[s] * L2E;
      float rs = 0.f;
      #pragma unroll
      for (int kb4 = 0; kb4 < 4; ++kb4) {
        float p0 = exp2f(fmaf(s_acc[s][kb4][0], L2E, -mb));
        float p1 = exp2f(fmaf(s_acc[s][kb4][1], L2E, -mb));
        float p2 = exp2f(fmaf(s_acc[s][kb4][2], L2E, -mb));
        float p3 = exp2f(fmaf(s_acc[s][kb4][3], L2E, -mb));
        rs += (p0 + p1) + (p2 + p3);
        uint2 pk = { pk_bf16(p0, p1), pk_bf16(p2, p3) };
        *(uint2*)&Ps[w][s * 16 + llo][kb4 * 16 + lhi * 4] = pk;
      }
      lsum[s] += rs;
    }

    // O += P V : V-frags read once, reused by both q-sets
    bf16x8 pa[2][2];
    #pragma unroll
    for (int s = 0; s < 2; ++s) {
      pa[s][0] = *(const bf16x8*)&Ps[w][s * 16 + llo][lhi * 8];
      pa[s][1] = *(const bf16x8*)&Ps[w][s * 16 + llo][32 + lhi * 8];
    }
    #pragma unroll
    for (int cb = 0; cb < 4; ++cb) {
      bf16x8 vf0 = *(const bf16x8*)&Vs[cb * 16 + llo][lhi * 8];
      bf16x8 vf1 = *(const bf16x8*)&Vs[cb * 16 + llo][32 + lhi * 8];
      #pragma unroll
      for (int s = 0; s < 2; ++s) {
        MFMA16(o_acc[s][cb], pa[s][0], vf0);
        MFMA16(o_acc[s][cb], pa[s][1], vf1);
      }
    }

    __syncthreads();                 // all waves done reading K/V tile kt
    if (kt < 31) {
      *(u16x8*)&Ks[kr][chs] = nk0;  *(u16x8*)&Ks[kr][chs + 8] = nk1;
      *(u16x8*)&Vs[kr][chs] = nv0;  *(u16x8*)&Vs[kr][chs + 8] = nv1;
    }
    __syncthreads();                 // next tile visible
  }

  // end: reduce lsum across the 4-lane q-group, normalize, write AO bf16
  const int b = bh / 12, h = bh % 12;
  #pragma unroll
  for (int s = 0; s < 2; ++s) {
    lsum[s] += __shfl_xor(lsum[s], 16);
    lsum[s] += __shfl_xor(lsum[s], 32);
    float ls[4];
    #pragma unroll
    for (int r = 0; r < 4; ++r) ls[r] = __shfl(lsum[s], lhi * 20 + r);
    #pragma unroll
    for (int cb = 0; cb < 4; ++cb)
      #pragma unroll
      for (int r = 0; r < 4; ++r) {
        const float val = o_acc[s][cb][r] / ls[r];
        AO[((size_t)(b * 2048 + q0w + s * 16 + lhi * 4 + r)) * 768 + h * 64 + cb * 16 + llo] = f2b(val);
      }
  }
}

// ---------------------------------------------------------------------------
// Kernel 3: out = AO @ Wot^T + bo, m97-style staging, XCD swizzle. fp32 out.
// ---------------------------------------------------------------------------
__global__ __launch_bounds__(256) void out_gemm_kernel(
    const u16* __restrict__ A, const u16* __restrict__ Wot,
    const float* __restrict__ bias, float* __restrict__ Out) {
  __shared__ u16 As[4096], Bs[4096];
  const int tid = threadIdx.x;
  const int w = tid >> 6, l = tid & 63;
  const int llo = l & 15, lhi = l >> 4;
  // XCD swizzle: 384 blocks, 48 per XCD
  const int id0 = blockIdx.y * 64 + blockIdx.x;
  const int swz = (id0 & 7) * 48 + (id0 >> 3);
  const int m0 = (swz & 63) * 128, n0 = (swz >> 6) * 128;
  const int wr = (w >> 1) * 64, wc = (w & 1) * 64;

  f32x4 acc[4][4] = {};

  const int sr = tid >> 2;
  const int sc = (tid & 3) * 8;
  const unsigned lb = ((unsigned)w) * 512;
  const u16* ap = A   + (size_t)(m0 + sr) * 768 + sc;
  const u16* bp = Wot + (size_t)(n0 + sr) * 768 + sc;
  const size_t half = (size_t)64 * 768;

  for (int k0 = 0; k0 < 768; k0 += 32) {
    __syncthreads();
    gload16(ap + k0,        As + lb);
    gload16(ap + half + k0, As + 2048 + lb);
    gload16(bp + k0,        Bs + lb);
    gload16(bp + half + k0, Bs + 2048 + lb);
    __syncthreads();
    bf16x8 af[4], bfr[4];
    #pragma unroll
    for (int i = 0; i < 4; ++i)
      af[i] = *(const bf16x8*)&As[(wr + i * 16 + llo) * 32 + lhi * 8];
    #pragma unroll
    for (int n = 0; n < 4; ++n)
      bfr[n] = *(const bf16x8*)&Bs[(wc + n * 16 + llo) * 32 + lhi * 8];
    #pragma unroll
    for (int i = 0; i < 4; ++i)
      #pragma unroll
      for (int n = 0; n < 4; ++n)
        MFMA16(acc[i][n], af[i], bfr[n]);
  }

  #pragma unroll
  for (int i = 0; i < 4; ++i)
    #pragma unroll
    for (int n = 0; n < 4; ++n) {
      const int gc = n0 + wc + n * 16 + llo;
      const float bb = bias[gc];
      #pragma unroll
      for (int r = 0; r < 4; ++r) {
        const int row = m0 + wr + i * 16 + lhi * 4 + r;
        Out[(size_t)row * 768 + gc] = acc[i][n][r] + bb;
      }
    }
}

// ---------------------------------------------------------------------------
extern "C" void kernel_launch(void* const* d_in, const int* in_sizes, int n_in,
                              void* d_out, int out_size, void* d_ws, size_t ws_size,
                              hipStream_t stream) {
  const float* x    = (const float*)d_in[0];
  const float* Wqkv = (const float*)d_in[1];
  const float* Wo   = (const float*)d_in[2];
  const float* bo   = (const float*)d_in[3];
  float* out = (float*)d_out;

  const size_t SEG = (size_t)48 * 2048 * 64;  // 6291456
  float* qf  = (float*)d_ws;                  // [SEG] fp32
  u16* kk    = (u16*)(qf + SEG);              // [SEG]
  u16* vt    = kk + SEG;                      // [SEG]
  u16* xh    = vt + SEG;                      // [SEG]  (becomes AO)
  u16* xl    = xh + SEG;                      // [SEG]
  u16* wth   = xl + SEG;                      // [2304*768]
  u16* wtl   = wth + (size_t)2304 * 768;
  u16* wot   = wtl + (size_t)2304 * 768;      // [768*768]
  u16* ao    = xh;                            // alias: Xh dead after qkv_gemm

  prep_x_kernel <<<dim3(6144), 256, 0, stream>>>(x, xh, xl);
  prep_w_kernel <<<dim3(24, 72), 256, 0, stream>>>(Wqkv, wth, wtl, 768, 2304);
  prep_wo_kernel<<<dim3(24, 24), 256, 0, stream>>>(Wo, wot, 768, 768);
  qkv_gemm_kernel<<<dim3(64, 18), 256, 0, stream>>>(xh, xl, wth, wtl, qf, kk, vt);
  attn_kernel   <<<dim3(16, 48), 256, 0, stream>>>(qf, kk, vt, ao);
  out_gemm_kernel<<<dim3(64, 6), 256, 0, stream>>>(ao, wot, bo, out);
}

// Round 7
// 235.847 us; speedup vs baseline: 1.1733x; 1.1733x over previous
//
#include <hip/hip_runtime.h>
#include <hip/hip_bf16.h>

// B=4, L=2048, DIM=768, H=12, C=64.  M = B*L = 8192.  BH = 48.
// ws (u16 units), SEG = 48*2048*64 = 6291456:
//   Qf32[2S] | K[S] | Vt[S] | Xh[S] (reused as AO after qkv) | Xl[S]
//   | WtH[2304*768] | WtL[2304*768] | Wot[768*768]   ~= 84 MB

typedef unsigned short u16;
typedef u16 u16x2 __attribute__((ext_vector_type(2)));
typedef u16 u16x4 __attribute__((ext_vector_type(4)));
typedef u16 u16x8 __attribute__((ext_vector_type(8)));
typedef short bf16x8 __attribute__((ext_vector_type(8)));
typedef float f32x4 __attribute__((ext_vector_type(4)));

#define MFMA16(acc, a, b) \
  asm("v_mfma_f32_16x16x32_bf16 %0, %1, %2, %0" : "+v"(acc) : "v"(a), "v"(b))

__device__ __forceinline__ u16 f2b(float f) {  // fp32 -> bf16 RNE
  unsigned u = __float_as_uint(f);
  return (u16)((u + 0x7fffu + ((u >> 16) & 1u)) >> 16);
}
__device__ __forceinline__ float b2f(u16 h) {
  return __uint_as_float(((unsigned)h) << 16);
}
__device__ __forceinline__ unsigned pk_bf16(float a, float b) {
  unsigned d;
  asm("v_cvt_pk_bf16_f32 %0, %1, %2" : "=v"(d) : "v"(a), "v"(b));
  return d;  // low16 = bf16(a), high16 = bf16(b)
}

// async global->LDS, 16B per lane. LDS dest must be wave-uniform base.
__device__ __forceinline__ void gload16(const u16* g, u16* l) {
  __builtin_amdgcn_global_load_lds(
      (const __attribute__((address_space(1))) unsigned*)g,
      (__attribute__((address_space(3))) unsigned*)l, 16, 0, 0);
}

// ---------------------------------------------------------------------------
// prep_x: x fp32 [8192][768] -> Xh, Xl bf16 (Dekker hi/lo). 4 elems/thread.
// ---------------------------------------------------------------------------
__global__ __launch_bounds__(256) void prep_x_kernel(
    const float* __restrict__ X, u16* __restrict__ Xh, u16* __restrict__ Xl) {
  const size_t i = ((size_t)blockIdx.x * 256 + threadIdx.x) * 4;
  float4 v = *(const float4*)(X + i);
  u16 h0 = f2b(v.x), h1 = f2b(v.y), h2 = f2b(v.z), h3 = f2b(v.w);
  u16x4 hs = { h0, h1, h2, h3 };
  u16x4 ls = { f2b(v.x - b2f(h0)), f2b(v.y - b2f(h1)),
               f2b(v.z - b2f(h2)), f2b(v.w - b2f(h3)) };
  *(u16x4*)(Xh + i) = hs;
  *(u16x4*)(Xl + i) = ls;
}

// ---------------------------------------------------------------------------
// prep_w: W fp32 [K][N] -> WtH/WtL bf16 [N][K] (transpose + split).
// ---------------------------------------------------------------------------
__global__ __launch_bounds__(256) void prep_w_kernel(
    const float* __restrict__ W, u16* __restrict__ WtH, u16* __restrict__ WtL,
    int K, int N) {
  __shared__ float T[32][33];
  const int k0 = blockIdx.x * 32, n0 = blockIdx.y * 32;
  const int tx = threadIdx.x & 31, ty = threadIdx.x >> 5;
  #pragma unroll
  for (int i = 0; i < 4; ++i)
    T[ty + i * 8][tx] = W[(size_t)(k0 + ty + i * 8) * N + n0 + tx];
  __syncthreads();
  #pragma unroll
  for (int i = 0; i < 4; ++i) {
    const int rn = ty + i * 8, ck = tx;
    float v = T[ck][rn];
    u16 h = f2b(v);
    WtH[(size_t)(n0 + rn) * K + k0 + ck] = h;
    WtL[(size_t)(n0 + rn) * K + k0 + ck] = f2b(v - b2f(h));
  }
}

// prep_wo: Wo fp32 [K][N] -> Wot bf16 [N][K] (transpose, hi only).
__global__ __launch_bounds__(256) void prep_wo_kernel(
    const float* __restrict__ W, u16* __restrict__ Wt, int K, int N) {
  __shared__ float T[32][33];
  const int k0 = blockIdx.x * 32, n0 = blockIdx.y * 32;
  const int tx = threadIdx.x & 31, ty = threadIdx.x >> 5;
  #pragma unroll
  for (int i = 0; i < 4; ++i)
    T[ty + i * 8][tx] = W[(size_t)(k0 + ty + i * 8) * N + n0 + tx];
  __syncthreads();
  #pragma unroll
  for (int i = 0; i < 4; ++i) {
    const int rn = ty + i * 8, ck = tx;
    Wt[(size_t)(n0 + rn) * K + k0 + ck] = f2b(T[ck][rn]);
  }
}

// ---------------------------------------------------------------------------
// Kernel 1: qkv = x @ Wqkv. Q/K panels (t<2): bf16x3 split, 3 MFMAs.
// V panels (t==2): hi*hi only (1 MFMA, half the staging) — V is stored bf16
// anyway and its error contribution is ~20x below budget.
// 128x128 tile, BK=32, 4 waves, global_load_lds w16. NO XCD swizzle
// (inputs are L3-resident; swizzle measured 5x over-fetch, R6).
// ---------------------------------------------------------------------------
__global__ __launch_bounds__(256) void qkv_gemm_kernel(
    const u16* __restrict__ Xh, const u16* __restrict__ Xl,
    const u16* __restrict__ WtH, const u16* __restrict__ WtL,
    float* __restrict__ Qo, u16* __restrict__ Ko, u16* __restrict__ Vo) {
  __shared__ u16 Ah[4096], Al[4096], Bh[4096], Bl[4096];  // [128][32] each
  const int tid = threadIdx.x;
  const int w = tid >> 6, l = tid & 63;
  const int llo = l & 15, lhi = l >> 4;
  const int m0 = blockIdx.x * 128, n0 = blockIdx.y * 128;
  const int t = blockIdx.y / 6;           // 0:Q 1:K 2:V (uniform per block)
  const int wr = (w >> 1) * 64, wc = (w & 1) * 64;

  f32x4 acc[4][4] = {};

  const int sr = tid >> 2;
  const int sc = (tid & 3) * 8;
  const unsigned lb = ((unsigned)w) * 512;
  const u16* axh = Xh + (size_t)(m0 + sr) * 768 + sc;
  const u16* axl = Xl + (size_t)(m0 + sr) * 768 + sc;
  const u16* bwh = WtH + (size_t)(n0 + sr) * 768 + sc;
  const u16* bwl = WtL + (size_t)(n0 + sr) * 768 + sc;
  const size_t half = (size_t)64 * 768;

  if (t < 2) {
    for (int k0 = 0; k0 < 768; k0 += 32) {
      __syncthreads();
      gload16(axh + k0,        Ah + lb);
      gload16(axh + half + k0, Ah + 2048 + lb);
      gload16(axl + k0,        Al + lb);
      gload16(axl + half + k0, Al + 2048 + lb);
      gload16(bwh + k0,        Bh + lb);
      gload16(bwh + half + k0, Bh + 2048 + lb);
      gload16(bwl + k0,        Bl + lb);
      gload16(bwl + half + k0, Bl + 2048 + lb);
      __syncthreads();
      bf16x8 ahf[4], alf[4], bhf[4], blf[4];
      #pragma unroll
      for (int i = 0; i < 4; ++i) {
        ahf[i] = *(const bf16x8*)&Ah[(wr + i * 16 + llo) * 32 + lhi * 8];
        alf[i] = *(const bf16x8*)&Al[(wr + i * 16 + llo) * 32 + lhi * 8];
      }
      #pragma unroll
      for (int n = 0; n < 4; ++n) {
        bhf[n] = *(const bf16x8*)&Bh[(wc + n * 16 + llo) * 32 + lhi * 8];
        blf[n] = *(const bf16x8*)&Bl[(wc + n * 16 + llo) * 32 + lhi * 8];
      }
      #pragma unroll
      for (int i = 0; i < 4; ++i)
        #pragma unroll
        for (int n = 0; n < 4; ++n) {
          MFMA16(acc[i][n], ahf[i], bhf[n]);
          MFMA16(acc[i][n], alf[i], bhf[n]);
          MFMA16(acc[i][n], ahf[i], blf[n]);
        }
    }
  } else {
    for (int k0 = 0; k0 < 768; k0 += 32) {
      __syncthreads();
      gload16(axh + k0,        Ah + lb);
      gload16(axh + half + k0, Ah + 2048 + lb);
      gload16(bwh + k0,        Bh + lb);
      gload16(bwh + half + k0, Bh + 2048 + lb);
      __syncthreads();
      bf16x8 ahf[4], bhf[4];
      #pragma unroll
      for (int i = 0; i < 4; ++i)
        ahf[i] = *(const bf16x8*)&Ah[(wr + i * 16 + llo) * 32 + lhi * 8];
      #pragma unroll
      for (int n = 0; n < 4; ++n)
        bhf[n] = *(const bf16x8*)&Bh[(wc + n * 16 + llo) * 32 + lhi * 8];
      #pragma unroll
      for (int i = 0; i < 4; ++i)
        #pragma unroll
        for (int n = 0; n < 4; ++n)
          MFMA16(acc[i][n], ahf[i], bhf[n]);
    }
  }

  #pragma unroll
  for (int i = 0; i < 4; ++i) {
    #pragma unroll
    for (int n = 0; n < 4; ++n) {
      const int gc = n0 + wc + n * 16 + llo;
      const int rem = gc - t * 768;
      const int h = rem >> 6, c = rem & 63;
      #pragma unroll
      for (int r = 0; r < 4; ++r) {
        const int row = m0 + wr + i * 16 + lhi * 4 + r;
        const int b = row >> 11, lq = row & 2047;
        const size_t bh_ = (size_t)(b * 12 + h);
        const float fv = acc[i][n][r];
        if (t == 0)      Qo[(bh_ * 2048 + lq) * 64 + c] = fv;
        else if (t == 1) Ko[(bh_ * 2048 + lq) * 64 + c] = f2b(fv);
        else             Vo[(bh_ * 64 + c) * 2048 + lq] = f2b(fv);
      }
    }
  }
}

// ---------------------------------------------------------------------------
// Kernel 2: flash attention. 4 waves x 32 q-rows = 128 q/block; each wave's
// K/V fragment reads serve TWO q-sets. Swapped-QK in-lane softmax; shfl-free
// common path. Single-buffer K/V, T14 async staging. XCD swizzle (K/V of a
// head clusters in one XCD's L2 — kept from R6, measured neutral-positive).
// ---------------------------------------------------------------------------
__global__ __launch_bounds__(256, 3) void attn_kernel(
    const float* __restrict__ Qf, const u16* __restrict__ Km,
    const u16* __restrict__ Vt, u16* __restrict__ AO) {
  __shared__ u16 Ks[64][72];
  __shared__ u16 Vs[64][72];
  __shared__ u16 Ps[4][32][72];   // [wave][q(2 sets x16)][key]
  const int tid = threadIdx.x;
  const int w = tid >> 6, l = tid & 63;
  const int llo = l & 15, lhi = l >> 4;
  const int id0 = blockIdx.y * 16 + blockIdx.x;
  const int swz = (id0 & 7) * 96 + (id0 >> 3);
  const int bh = swz >> 4;
  const int q0w = (swz & 15) * 128 + w * 32;

  // staging coords: thread covers 32B (16 u16) of each 64x64 tile
  const int kr = tid >> 2, chs = (tid & 3) * 16;
  const u16* Kp = Km + ((size_t)bh * 2048 + kr) * 64 + chs;
  const u16* Vp = Vt + ((size_t)bh * 64 + kr) * 2048 + chs;

  // Q fragments (2 q-sets, hi/lo): lane holds Q[q=llo][c=lhi*8+j]
  bf16x8 qh[2][2], ql[2][2];
  #pragma unroll
  for (int s = 0; s < 2; ++s) {
    const float* Qp = Qf + ((size_t)bh * 2048 + q0w + s * 16 + llo) * 64 + lhi * 8;
    #pragma unroll
    for (int j = 0; j < 8; ++j) {
      float a = Qp[j], b = Qp[32 + j];
      u16 ha = f2b(a), hb = f2b(b);
      qh[s][0][j] = (short)ha; ql[s][0][j] = (short)f2b(a - b2f(ha));
      qh[s][1][j] = (short)hb; ql[s][1][j] = (short)f2b(b - b2f(hb));
    }
  }

  const float L2E = 1.4426950408889634f;
  float mrow[2] = { -1e30f, -1e30f };   // group-uniform (updated on rescale)
  float lsum[2] = { 0.f, 0.f };         // per-lane partial (own 16 keys)
  f32x4 o_acc[2][4] = {};               // [set][cb]: O[q=lhi*4+r][c=cb*16+llo]

  { // prologue: stage tile 0
    u16x8 k0 = *(const u16x8*)(Kp),     k1 = *(const u16x8*)(Kp + 8);
    u16x8 v0 = *(const u16x8*)(Vp),     v1 = *(const u16x8*)(Vp + 8);
    *(u16x8*)&Ks[kr][chs] = k0;  *(u16x8*)&Ks[kr][chs + 8] = k1;
    *(u16x8*)&Vs[kr][chs] = v0;  *(u16x8*)&Vs[kr][chs + 8] = v1;
  }
  __syncthreads();

  for (int kt = 0; kt < 32; ++kt) {
    // T14: issue next-tile loads before compute (vmcnt waits land at ds_write)
    u16x8 nk0, nk1, nv0, nv1;
    if (kt < 31) {
      const u16* kp = Kp + (size_t)(kt + 1) * 4096;
      const u16* vp = Vp + (size_t)(kt + 1) * 64;
      nk0 = *(const u16x8*)(kp);      nk1 = *(const u16x8*)(kp + 8);
      nv0 = *(const u16x8*)(vp);      nv1 = *(const u16x8*)(vp + 8);
    }

    // S^T: s_acc[s][kb4] reg r = S[key=kb4*16+lhi*4+r][q(set s)=llo]
    f32x4 s_acc[2][4] = {};
    #pragma unroll
    for (int kb4 = 0; kb4 < 4; ++kb4) {
      bf16x8 kf0 = *(const bf16x8*)&Ks[kb4 * 16 + llo][lhi * 8];
      bf16x8 kf1 = *(const bf16x8*)&Ks[kb4 * 16 + llo][32 + lhi * 8];
      #pragma unroll
      for (int s = 0; s < 2; ++s) {
        MFMA16(s_acc[s][kb4], kf0, qh[s][0]);
        MFMA16(s_acc[s][kb4], kf0, ql[s][0]);
        MFMA16(s_acc[s][kb4], kf1, qh[s][1]);
        MFMA16(s_acc[s][kb4], kf1, ql[s][1]);
      }
    }

    // per-lane tile max per set (no shfl on common path)
    float tm[2];
    #pragma unroll
    for (int s = 0; s < 2; ++s) {
      float a = fmaxf(fmaxf(s_acc[s][0][0], s_acc[s][0][1]), fmaxf(s_acc[s][0][2], s_acc[s][0][3]));
      float b = fmaxf(fmaxf(s_acc[s][1][0], s_acc[s][1][1]), fmaxf(s_acc[s][1][2], s_acc[s][1][3]));
      float c = fmaxf(fmaxf(s_acc[s][2][0], s_acc[s][2][1]), fmaxf(s_acc[s][2][2], s_acc[s][2][3]));
      float d = fmaxf(fmaxf(s_acc[s][3][0], s_acc[s][3][1]), fmaxf(s_acc[s][3][2], s_acc[s][3][3]));
      tm[s] = fmaxf(fmaxf(a, b), fmaxf(c, d));
    }

    // defer-max: rescale (rare) when any lane's partial max grew past THR=8
    if (!__all(tm[0] <= mrow[0] + 8.f && tm[1] <= mrow[1] + 8.f)) {
      #pragma unroll
      for (int s = 0; s < 2; ++s) {
        float g = tm[s];
        g = fmaxf(g, __shfl_xor(g, 16));
        g = fmaxf(g, __shfl_xor(g, 32));
        const float mn = fmaxf(mrow[s], g);
        const float scale = __expf(mrow[s] - mn);
        mrow[s] = mn;
        lsum[s] *= scale;
        float scr[4];
        #pragma unroll
        for (int r = 0; r < 4; ++r) scr[r] = __shfl(scale, lhi * 20 + r);
        #pragma unroll
        for (int cb = 0; cb < 4; ++cb)
          #pragma unroll
          for (int r = 0; r < 4; ++r) o_acc[s][cb][r] *= scr[r];
      }
    }

    // P = exp(S - mrow), packed bf16 stores; lsum accumulates per-lane
    #pragma unroll
    for (int s = 0; s < 2; ++s) {
      const float mb = mrow[s] * L2E;
      float rs = 0.f;
      #pragma unroll
      for (int kb4 = 0; kb4 < 4; ++kb4) {
        float p0 = exp2f(fmaf(s_acc[s][kb4][0], L2E, -mb));
        float p1 = exp2f(fmaf(s_acc[s][kb4][1], L2E, -mb));
        float p2 = exp2f(fmaf(s_acc[s][kb4][2], L2E, -mb));
        float p3 = exp2f(fmaf(s_acc[s][kb4][3], L2E, -mb));
        rs += (p0 + p1) + (p2 + p3);
        uint2 pk = { pk_bf16(p0, p1), pk_bf16(p2, p3) };
        *(uint2*)&Ps[w][s * 16 + llo][kb4 * 16 + lhi * 4] = pk;
      }
      lsum[s] += rs;
    }

    // O += P V : V-frags read once, reused by both q-sets
    bf16x8 pa[2][2];
    #pragma unroll
    for (int s = 0; s < 2; ++s) {
      pa[s][0] = *(const bf16x8*)&Ps[w][s * 16 + llo][lhi * 8];
      pa[s][1] = *(const bf16x8*)&Ps[w][s * 16 + llo][32 + lhi * 8];
    }
    #pragma unroll
    for (int cb = 0; cb < 4; ++cb) {
      bf16x8 vf0 = *(const bf16x8*)&Vs[cb * 16 + llo][lhi * 8];
      bf16x8 vf1 = *(const bf16x8*)&Vs[cb * 16 + llo][32 + lhi * 8];
      #pragma unroll
      for (int s = 0; s < 2; ++s) {
        MFMA16(o_acc[s][cb], pa[s][0], vf0);
        MFMA16(o_acc[s][cb], pa[s][1], vf1);
      }
    }

    __syncthreads();                 // all waves done reading K/V tile kt
    if (kt < 31) {
      *(u16x8*)&Ks[kr][chs] = nk0;  *(u16x8*)&Ks[kr][chs + 8] = nk1;
      *(u16x8*)&Vs[kr][chs] = nv0;  *(u16x8*)&Vs[kr][chs + 8] = nv1;
    }
    __syncthreads();                 // next tile visible
  }

  // end: reduce lsum across the 4-lane q-group, normalize, write AO bf16
  const int b = bh / 12, h = bh % 12;
  #pragma unroll
  for (int s = 0; s < 2; ++s) {
    lsum[s] += __shfl_xor(lsum[s], 16);
    lsum[s] += __shfl_xor(lsum[s], 32);
    float ls[4];
    #pragma unroll
    for (int r = 0; r < 4; ++r) ls[r] = __shfl(lsum[s], lhi * 20 + r);
    #pragma unroll
    for (int cb = 0; cb < 4; ++cb)
      #pragma unroll
      for (int r = 0; r < 4; ++r) {
        const float val = o_acc[s][cb][r] / ls[r];
        AO[((size_t)(b * 2048 + q0w + s * 16 + lhi * 4 + r)) * 768 + h * 64 + cb * 16 + llo] = f2b(val);
      }
  }
}

// ---------------------------------------------------------------------------
// Kernel 3: out = AO @ Wot^T + bo, m97-style staging, no swizzle. fp32 out.
// ---------------------------------------------------------------------------
__global__ __launch_bounds__(256) void out_gemm_kernel(
    const u16* __restrict__ A, const u16* __restrict__ Wot,
    const float* __restrict__ bias, float* __restrict__ Out) {
  __shared__ u16 As[4096], Bs[4096];
  const int tid = threadIdx.x;
  const int w = tid >> 6, l = tid & 63;
  const int llo = l & 15, lhi = l >> 4;
  const int m0 = blockIdx.x * 128, n0 = blockIdx.y * 128;
  const int wr = (w >> 1) * 64, wc = (w & 1) * 64;

  f32x4 acc[4][4] = {};

  const int sr = tid >> 2;
  const int sc = (tid & 3) * 8;
  const unsigned lb = ((unsigned)w) * 512;
  const u16* ap = A   + (size_t)(m0 + sr) * 768 + sc;
  const u16* bp = Wot + (size_t)(n0 + sr) * 768 + sc;
  const size_t half = (size_t)64 * 768;

  for (int k0 = 0; k0 < 768; k0 += 32) {
    __syncthreads();
    gload16(ap + k0,        As + lb);
    gload16(ap + half + k0, As + 2048 + lb);
    gload16(bp + k0,        Bs + lb);
    gload16(bp + half + k0, Bs + 2048 + lb);
    __syncthreads();
    bf16x8 af[4], bfr[4];
    #pragma unroll
    for (int i = 0; i < 4; ++i)
      af[i] = *(const bf16x8*)&As[(wr + i * 16 + llo) * 32 + lhi * 8];
    #pragma unroll
    for (int n = 0; n < 4; ++n)
      bfr[n] = *(const bf16x8*)&Bs[(wc + n * 16 + llo) * 32 + lhi * 8];
    #pragma unroll
    for (int i = 0; i < 4; ++i)
      #pragma unroll
      for (int n = 0; n < 4; ++n)
        MFMA16(acc[i][n], af[i], bfr[n]);
  }

  #pragma unroll
  for (int i = 0; i < 4; ++i)
    #pragma unroll
    for (int n = 0; n < 4; ++n) {
      const int gc = n0 + wc + n * 16 + llo;
      const float bb = bias[gc];
      #pragma unroll
      for (int r = 0; r < 4; ++r) {
        const int row = m0 + wr + i * 16 + lhi * 4 + r;
        Out[(size_t)row * 768 + gc] = acc[i][n][r] + bb;
      }
    }
}

// ---------------------------------------------------------------------------
extern "C" void kernel_launch(void* const* d_in, const int* in_sizes, int n_in,
                              void* d_out, int out_size, void* d_ws, size_t ws_size,
                              hipStream_t stream) {
  const float* x    = (const float*)d_in[0];
  const float* Wqkv = (const float*)d_in[1];
  const float* Wo   = (const float*)d_in[2];
  const float* bo   = (const float*)d_in[3];
  float* out = (float*)d_out;

  const size_t SEG = (size_t)48 * 2048 * 64;  // 6291456
  float* qf  = (float*)d_ws;                  // [SEG] fp32
  u16* kk    = (u16*)(qf + SEG);              // [SEG]
  u16* vt    = kk + SEG;                      // [SEG]
  u16* xh    = vt + SEG;                      // [SEG]  (becomes AO)
  u16* xl    = xh + SEG;                      // [SEG]
  u16* wth   = xl + SEG;                      // [2304*768]
  u16* wtl   = wth + (size_t)2304 * 768;
  u16* wot   = wtl + (size_t)2304 * 768;      // [768*768]
  u16* ao    = xh;                            // alias: Xh dead after qkv_gemm

  prep_x_kernel <<<dim3(6144), 256, 0, stream>>>(x, xh, xl);
  prep_w_kernel <<<dim3(24, 72), 256, 0, stream>>>(Wqkv, wth, wtl, 768, 2304);
  prep_wo_kernel<<<dim3(24, 24), 256, 0, stream>>>(Wo, wot, 768, 768);
  qkv_gemm_kernel<<<dim3(64, 18), 256, 0, stream>>>(xh, xl, wth, wtl, qf, kk, vt);
  attn_kernel   <<<dim3(16, 48), 256, 0, stream>>>(qf, kk, vt, ao);
  out_gemm_kernel<<<dim3(64, 6), 256, 0, stream>>>(ao, wot, bo, out);
}

// Round 8
// 234.941 us; speedup vs baseline: 1.1778x; 1.0039x over previous
//
#include <hip/hip_runtime.h>
#include <hip/hip_bf16.h>

// B=4, L=2048, DIM=768, H=12, C=64.  M = B*L = 8192.  BH = 48.
// ws (u16 units), SEG = 48*2048*64 = 6291456:
//   Qf32[2S] | K[S] | Vt[S] | Xh[S] (reused as AO after qkv) | Xl[S]
//   | WtH[2304*768] | WtL[2304*768] | Wot[768*768]   ~= 84 MB

typedef unsigned short u16;
typedef u16 u16x2 __attribute__((ext_vector_type(2)));
typedef u16 u16x4 __attribute__((ext_vector_type(4)));
typedef u16 u16x8 __attribute__((ext_vector_type(8)));
typedef short bf16x8 __attribute__((ext_vector_type(8)));
typedef float f32x4 __attribute__((ext_vector_type(4)));

#define MFMA16(acc, a, b) \
  asm("v_mfma_f32_16x16x32_bf16 %0, %1, %2, %0" : "+v"(acc) : "v"(a), "v"(b))

__device__ __forceinline__ u16 f2b(float f) {  // fp32 -> bf16 RNE
  unsigned u = __float_as_uint(f);
  return (u16)((u + 0x7fffu + ((u >> 16) & 1u)) >> 16);
}
__device__ __forceinline__ float b2f(u16 h) {
  return __uint_as_float(((unsigned)h) << 16);
}
__device__ __forceinline__ unsigned pk_bf16(float a, float b) {
  unsigned d;
  asm("v_cvt_pk_bf16_f32 %0, %1, %2" : "=v"(d) : "v"(a), "v"(b));
  return d;  // low16 = bf16(a), high16 = bf16(b)
}

// async global->LDS, 16B per lane. LDS dest must be wave-uniform base.
__device__ __forceinline__ void gload16(const u16* g, u16* l) {
  __builtin_amdgcn_global_load_lds(
      (const __attribute__((address_space(1))) unsigned*)g,
      (__attribute__((address_space(3))) unsigned*)l, 16, 0, 0);
}

// ---------------------------------------------------------------------------
// prep_x: x fp32 [8192][768] -> Xh, Xl bf16 (Dekker hi/lo). 4 elems/thread.
// ---------------------------------------------------------------------------
__global__ __launch_bounds__(256) void prep_x_kernel(
    const float* __restrict__ X, u16* __restrict__ Xh, u16* __restrict__ Xl) {
  const size_t i = ((size_t)blockIdx.x * 256 + threadIdx.x) * 4;
  float4 v = *(const float4*)(X + i);
  u16 h0 = f2b(v.x), h1 = f2b(v.y), h2 = f2b(v.z), h3 = f2b(v.w);
  u16x4 hs = { h0, h1, h2, h3 };
  u16x4 ls = { f2b(v.x - b2f(h0)), f2b(v.y - b2f(h1)),
               f2b(v.z - b2f(h2)), f2b(v.w - b2f(h3)) };
  *(u16x4*)(Xh + i) = hs;
  *(u16x4*)(Xl + i) = ls;
}

// ---------------------------------------------------------------------------
// prep_w: W fp32 [K][N] -> WtH/WtL bf16 [N][K] (transpose + split).
// ---------------------------------------------------------------------------
__global__ __launch_bounds__(256) void prep_w_kernel(
    const float* __restrict__ W, u16* __restrict__ WtH, u16* __restrict__ WtL,
    int K, int N) {
  __shared__ float T[32][33];
  const int k0 = blockIdx.x * 32, n0 = blockIdx.y * 32;
  const int tx = threadIdx.x & 31, ty = threadIdx.x >> 5;
  #pragma unroll
  for (int i = 0; i < 4; ++i)
    T[ty + i * 8][tx] = W[(size_t)(k0 + ty + i * 8) * N + n0 + tx];
  __syncthreads();
  #pragma unroll
  for (int i = 0; i < 4; ++i) {
    const int rn = ty + i * 8, ck = tx;
    float v = T[ck][rn];
    u16 h = f2b(v);
    WtH[(size_t)(n0 + rn) * K + k0 + ck] = h;
    WtL[(size_t)(n0 + rn) * K + k0 + ck] = f2b(v - b2f(h));
  }
}

// prep_wo: Wo fp32 [K][N] -> Wot bf16 [N][K] (transpose, hi only).
__global__ __launch_bounds__(256) void prep_wo_kernel(
    const float* __restrict__ W, u16* __restrict__ Wt, int K, int N) {
  __shared__ float T[32][33];
  const int k0 = blockIdx.x * 32, n0 = blockIdx.y * 32;
  const int tx = threadIdx.x & 31, ty = threadIdx.x >> 5;
  #pragma unroll
  for (int i = 0; i < 4; ++i)
    T[ty + i * 8][tx] = W[(size_t)(k0 + ty + i * 8) * N + n0 + tx];
  __syncthreads();
  #pragma unroll
  for (int i = 0; i < 4; ++i) {
    const int rn = ty + i * 8, ck = tx;
    Wt[(size_t)(n0 + rn) * K + k0 + ck] = f2b(T[ck][rn]);
  }
}

// ---------------------------------------------------------------------------
// Kernel 1: qkv = x @ Wqkv. Q/K panels (t<2): bf16x3 split, 3 MFMAs.
// V panels (t==2): hi*hi only (1 MFMA, half the staging).
// 128x128 tile, BK=32, 4 waves, global_load_lds w16. NO XCD swizzle
// (inputs are L3-resident; swizzle measured 5x over-fetch, R6).
// ---------------------------------------------------------------------------
__global__ __launch_bounds__(256) void qkv_gemm_kernel(
    const u16* __restrict__ Xh, const u16* __restrict__ Xl,
    const u16* __restrict__ WtH, const u16* __restrict__ WtL,
    float* __restrict__ Qo, u16* __restrict__ Ko, u16* __restrict__ Vo) {
  __shared__ u16 Ah[4096], Al[4096], Bh[4096], Bl[4096];  // [128][32] each
  const int tid = threadIdx.x;
  const int w = tid >> 6, l = tid & 63;
  const int llo = l & 15, lhi = l >> 4;
  const int m0 = blockIdx.x * 128, n0 = blockIdx.y * 128;
  const int t = blockIdx.y / 6;           // 0:Q 1:K 2:V (uniform per block)
  const int wr = (w >> 1) * 64, wc = (w & 1) * 64;

  f32x4 acc[4][4] = {};

  const int sr = tid >> 2;
  const int sc = (tid & 3) * 8;
  const unsigned lb = ((unsigned)w) * 512;
  const u16* axh = Xh + (size_t)(m0 + sr) * 768 + sc;
  const u16* axl = Xl + (size_t)(m0 + sr) * 768 + sc;
  const u16* bwh = WtH + (size_t)(n0 + sr) * 768 + sc;
  const u16* bwl = WtL + (size_t)(n0 + sr) * 768 + sc;
  const size_t half = (size_t)64 * 768;

  if (t < 2) {
    for (int k0 = 0; k0 < 768; k0 += 32) {
      __syncthreads();
      gload16(axh + k0,        Ah + lb);
      gload16(axh + half + k0, Ah + 2048 + lb);
      gload16(axl + k0,        Al + lb);
      gload16(axl + half + k0, Al + 2048 + lb);
      gload16(bwh + k0,        Bh + lb);
      gload16(bwh + half + k0, Bh + 2048 + lb);
      gload16(bwl + k0,        Bl + lb);
      gload16(bwl + half + k0, Bl + 2048 + lb);
      __syncthreads();
      bf16x8 ahf[4], alf[4], bhf[4], blf[4];
      #pragma unroll
      for (int i = 0; i < 4; ++i) {
        ahf[i] = *(const bf16x8*)&Ah[(wr + i * 16 + llo) * 32 + lhi * 8];
        alf[i] = *(const bf16x8*)&Al[(wr + i * 16 + llo) * 32 + lhi * 8];
      }
      #pragma unroll
      for (int n = 0; n < 4; ++n) {
        bhf[n] = *(const bf16x8*)&Bh[(wc + n * 16 + llo) * 32 + lhi * 8];
        blf[n] = *(const bf16x8*)&Bl[(wc + n * 16 + llo) * 32 + lhi * 8];
      }
      #pragma unroll
      for (int i = 0; i < 4; ++i)
        #pragma unroll
        for (int n = 0; n < 4; ++n) {
          MFMA16(acc[i][n], ahf[i], bhf[n]);
          MFMA16(acc[i][n], alf[i], bhf[n]);
          MFMA16(acc[i][n], ahf[i], blf[n]);
        }
    }
  } else {
    for (int k0 = 0; k0 < 768; k0 += 32) {
      __syncthreads();
      gload16(axh + k0,        Ah + lb);
      gload16(axh + half + k0, Ah + 2048 + lb);
      gload16(bwh + k0,        Bh + lb);
      gload16(bwh + half + k0, Bh + 2048 + lb);
      __syncthreads();
      bf16x8 ahf[4], bhf[4];
      #pragma unroll
      for (int i = 0; i < 4; ++i)
        ahf[i] = *(const bf16x8*)&Ah[(wr + i * 16 + llo) * 32 + lhi * 8];
      #pragma unroll
      for (int n = 0; n < 4; ++n)
        bhf[n] = *(const bf16x8*)&Bh[(wc + n * 16 + llo) * 32 + lhi * 8];
      #pragma unroll
      for (int i = 0; i < 4; ++i)
        #pragma unroll
        for (int n = 0; n < 4; ++n)
          MFMA16(acc[i][n], ahf[i], bhf[n]);
    }
  }

  #pragma unroll
  for (int i = 0; i < 4; ++i) {
    #pragma unroll
    for (int n = 0; n < 4; ++n) {
      const int gc = n0 + wc + n * 16 + llo;
      const int rem = gc - t * 768;
      const int h = rem >> 6, c = rem & 63;
      #pragma unroll
      for (int r = 0; r < 4; ++r) {
        const int row = m0 + wr + i * 16 + lhi * 4 + r;
        const int b = row >> 11, lq = row & 2047;
        const size_t bh_ = (size_t)(b * 12 + h);
        const float fv = acc[i][n][r];
        if (t == 0)      Qo[(bh_ * 2048 + lq) * 64 + c] = fv;
        else if (t == 1) Ko[(bh_ * 2048 + lq) * 64 + c] = f2b(fv);
        else             Vo[(bh_ * 64 + c) * 2048 + lq] = f2b(fv);
      }
    }
  }
}

// ---------------------------------------------------------------------------
// Kernel 2: flash attention. 4 waves x 32 q-rows. T2 XOR-swizzled LDS
// (unpadded 128B rows, byte ^= (row&7)<<4 on write AND read; all hot rows
// have row&7 == llo&7 so the swizzle is a per-lane constant). Double-buffered
// K/V with ONE barrier per tile (write buf^1 after compute). T14 early loads.
// ---------------------------------------------------------------------------
__global__ __launch_bounds__(256, 3) void attn_kernel(
    const float* __restrict__ Qf, const u16* __restrict__ Km,
    const u16* __restrict__ Vt, u16* __restrict__ AO) {
  __shared__ u16 KsB[2][64 * 64];   // 8 KB each, swizzled rows of 128 B
  __shared__ u16 VsB[2][64 * 64];
  __shared__ u16 PsB[4][32 * 64];   // per-wave P, swizzled rows of 128 B
  const int tid = threadIdx.x;
  const int w = tid >> 6, l = tid & 63;
  const int llo = l & 15, lhi = l >> 4;
  const int id0 = blockIdx.y * 16 + blockIdx.x;
  const int swzb = (id0 & 7) * 96 + (id0 >> 3);
  const int bh = swzb >> 4;
  const int q0w = (swzb & 15) * 128 + w * 32;

  const int sw = (llo & 7) << 4;            // frag byte swizzle (lane const)
  // staging coords: thread covers 32B (two 16B slots) of each 64x64 tile
  const int kr = tid >> 2;
  const int cs = (tid & 3) * 32;
  const int swk = (kr & 7) << 4;
  const int c0 = cs ^ swk, c1 = (cs ^ 16) ^ swk;
  const u16* Kp = Km + ((size_t)bh * 2048 + kr) * 64 + (tid & 3) * 16;
  const u16* Vp = Vt + ((size_t)bh * 64 + kr) * 2048 + (tid & 3) * 16;

  // Q fragments (2 q-sets, hi/lo): lane holds Q[q=llo][c=lhi*8+j]
  bf16x8 qh[2][2], ql[2][2];
  #pragma unroll
  for (int s = 0; s < 2; ++s) {
    const float* Qp = Qf + ((size_t)bh * 2048 + q0w + s * 16 + llo) * 64 + lhi * 8;
    #pragma unroll
    for (int j = 0; j < 8; ++j) {
      float a = Qp[j], b = Qp[32 + j];
      u16 ha = f2b(a), hb = f2b(b);
      qh[s][0][j] = (short)ha; ql[s][0][j] = (short)f2b(a - b2f(ha));
      qh[s][1][j] = (short)hb; ql[s][1][j] = (short)f2b(b - b2f(hb));
    }
  }

  const float L2E = 1.4426950408889634f;
  float mrow[2] = { -1e30f, -1e30f };   // group-uniform (updated on rescale)
  float lsum[2] = { 0.f, 0.f };         // per-lane partial (own 16 keys)
  f32x4 o_acc[2][4] = {};               // [set][cb]: O[q=lhi*4+r][c=cb*16+llo]
  char* const pb = (char*)PsB[w];

  { // prologue: stage tile 0 into buffer 0 (swizzled)
    u16x8 a = *(const u16x8*)(Kp), b = *(const u16x8*)(Kp + 8);
    u16x8 c = *(const u16x8*)(Vp), d = *(const u16x8*)(Vp + 8);
    char* kb = (char*)KsB[0];  char* vb = (char*)VsB[0];
    *(u16x8*)(kb + kr * 128 + c0) = a;  *(u16x8*)(kb + kr * 128 + c1) = b;
    *(u16x8*)(vb + kr * 128 + c0) = c;  *(u16x8*)(vb + kr * 128 + c1) = d;
  }
  __syncthreads();

  for (int kt = 0; kt < 32; ++kt) {
    const int cur = kt & 1;
    char* const kb = (char*)KsB[cur];
    char* const vb = (char*)VsB[cur];
    // T14: issue next-tile loads first (latency hides under compute)
    u16x8 nk0, nk1, nv0, nv1;
    if (kt < 31) {
      const u16* kp = Kp + (size_t)(kt + 1) * 4096;
      const u16* vp = Vp + (size_t)(kt + 1) * 64;
      nk0 = *(const u16x8*)(kp);  nk1 = *(const u16x8*)(kp + 8);
      nv0 = *(const u16x8*)(vp);  nv1 = *(const u16x8*)(vp + 8);
    }

    // S^T: s_acc[s][kb4] reg r = S[key=kb4*16+lhi*4+r][q(set s)=llo]
    f32x4 s_acc[2][4] = {};
    #pragma unroll
    for (int kb4 = 0; kb4 < 4; ++kb4) {
      const int row = kb4 * 16 + llo;
      bf16x8 kf0 = *(const bf16x8*)(kb + row * 128 + ((lhi * 16) ^ sw));
      bf16x8 kf1 = *(const bf16x8*)(kb + row * 128 + ((64 + lhi * 16) ^ sw));
      #pragma unroll
      for (int s = 0; s < 2; ++s) {
        MFMA16(s_acc[s][kb4], kf0, qh[s][0]);
        MFMA16(s_acc[s][kb4], kf0, ql[s][0]);
        MFMA16(s_acc[s][kb4], kf1, qh[s][1]);
        MFMA16(s_acc[s][kb4], kf1, ql[s][1]);
      }
    }

    // per-lane tile max per set (no shfl on common path)
    float tm[2];
    #pragma unroll
    for (int s = 0; s < 2; ++s) {
      float a = fmaxf(fmaxf(s_acc[s][0][0], s_acc[s][0][1]), fmaxf(s_acc[s][0][2], s_acc[s][0][3]));
      float b = fmaxf(fmaxf(s_acc[s][1][0], s_acc[s][1][1]), fmaxf(s_acc[s][1][2], s_acc[s][1][3]));
      float c = fmaxf(fmaxf(s_acc[s][2][0], s_acc[s][2][1]), fmaxf(s_acc[s][2][2], s_acc[s][2][3]));
      float d = fmaxf(fmaxf(s_acc[s][3][0], s_acc[s][3][1]), fmaxf(s_acc[s][3][2], s_acc[s][3][3]));
      tm[s] = fmaxf(fmaxf(a, b), fmaxf(c, d));
    }

    // defer-max: rescale (rare) when any lane's partial max grew past THR=8
    if (!__all(tm[0] <= mrow[0] + 8.f && tm[1] <= mrow[1] + 8.f)) {
      #pragma unroll
      for (int s = 0; s < 2; ++s) {
        float g = tm[s];
        g = fmaxf(g, __shfl_xor(g, 16));
        g = fmaxf(g, __shfl_xor(g, 32));
        const float mn = fmaxf(mrow[s], g);
        const float scale = __expf(mrow[s] - mn);
        mrow[s] = mn;
        lsum[s] *= scale;
        float scr[4];
        #pragma unroll
        for (int r = 0; r < 4; ++r) scr[r] = __shfl(scale, lhi * 20 + r);
        #pragma unroll
        for (int cb = 0; cb < 4; ++cb)
          #pragma unroll
          for (int r = 0; r < 4; ++r) o_acc[s][cb][r] *= scr[r];
      }
    }

    // P = exp(S - mrow), packed bf16 stores (swizzled 8B), per-lane lsum
    #pragma unroll
    for (int s = 0; s < 2; ++s) {
      const float mb = mrow[s] * L2E;
      float rs = 0.f;
      const int rq = s * 16 + llo;           // rq & 7 == llo & 7
      #pragma unroll
      for (int kb4 = 0; kb4 < 4; ++kb4) {
        float p0 = exp2f(fmaf(s_acc[s][kb4][0], L2E, -mb));
        float p1 = exp2f(fmaf(s_acc[s][kb4][1], L2E, -mb));
        float p2 = exp2f(fmaf(s_acc[s][kb4][2], L2E, -mb));
        float p3 = exp2f(fmaf(s_acc[s][kb4][3], L2E, -mb));
        rs += (p0 + p1) + (p2 + p3);
        uint2 pk = { pk_bf16(p0, p1), pk_bf16(p2, p3) };
        *(uint2*)(pb + rq * 128 + ((kb4 * 32 + lhi * 8) ^ sw)) = pk;
      }
      lsum[s] += rs;
    }

    // O += P V : V-frags read once, reused by both q-sets (all swizzled)
    bf16x8 pa[2][2];
    #pragma unroll
    for (int s = 0; s < 2; ++s) {
      const int rq = s * 16 + llo;
      pa[s][0] = *(const bf16x8*)(pb + rq * 128 + ((lhi * 16) ^ sw));
      pa[s][1] = *(const bf16x8*)(pb + rq * 128 + ((64 + lhi * 16) ^ sw));
    }
    #pragma unroll
    for (int cb = 0; cb < 4; ++cb) {
      const int row = cb * 16 + llo;
      bf16x8 vf0 = *(const bf16x8*)(vb + row * 128 + ((lhi * 16) ^ sw));
      bf16x8 vf1 = *(const bf16x8*)(vb + row * 128 + ((64 + lhi * 16) ^ sw));
      #pragma unroll
      for (int s = 0; s < 2; ++s) {
        MFMA16(o_acc[s][cb], pa[s][0], vf0);
        MFMA16(o_acc[s][cb], pa[s][1], vf1);
      }
    }

    // write next tile into the other buffer; prior iter's barrier guarantees
    // everyone already finished reading it. ONE barrier per tile.
    if (kt < 31) {
      char* kn = (char*)KsB[cur ^ 1];  char* vn = (char*)VsB[cur ^ 1];
      *(u16x8*)(kn + kr * 128 + c0) = nk0;  *(u16x8*)(kn + kr * 128 + c1) = nk1;
      *(u16x8*)(vn + kr * 128 + c0) = nv0;  *(u16x8*)(vn + kr * 128 + c1) = nv1;
    }
    __syncthreads();
  }

  // end: reduce lsum across the 4-lane q-group, normalize, write AO bf16
  const int b = bh / 12, h = bh % 12;
  #pragma unroll
  for (int s = 0; s < 2; ++s) {
    lsum[s] += __shfl_xor(lsum[s], 16);
    lsum[s] += __shfl_xor(lsum[s], 32);
    float ls[4];
    #pragma unroll
    for (int r = 0; r < 4; ++r) ls[r] = __shfl(lsum[s], lhi * 20 + r);
    #pragma unroll
    for (int cb = 0; cb < 4; ++cb)
      #pragma unroll
      for (int r = 0; r < 4; ++r) {
        const float val = o_acc[s][cb][r] / ls[r];
        AO[((size_t)(b * 2048 + q0w + s * 16 + lhi * 4 + r)) * 768 + h * 64 + cb * 16 + llo] = f2b(val);
      }
  }
}

// ---------------------------------------------------------------------------
// Kernel 3: out = AO @ Wot^T + bo, m97-style staging, no swizzle. fp32 out.
// ---------------------------------------------------------------------------
__global__ __launch_bounds__(256) void out_gemm_kernel(
    const u16* __restrict__ A, const u16* __restrict__ Wot,
    const float* __restrict__ bias, float* __restrict__ Out) {
  __shared__ u16 As[4096], Bs[4096];
  const int tid = threadIdx.x;
  const int w = tid >> 6, l = tid & 63;
  const int llo = l & 15, lhi = l >> 4;
  const int m0 = blockIdx.x * 128, n0 = blockIdx.y * 128;
  const int wr = (w >> 1) * 64, wc = (w & 1) * 64;

  f32x4 acc[4][4] = {};

  const int sr = tid >> 2;
  const int sc = (tid & 3) * 8;
  const unsigned lb = ((unsigned)w) * 512;
  const u16* ap = A   + (size_t)(m0 + sr) * 768 + sc;
  const u16* bp = Wot + (size_t)(n0 + sr) * 768 + sc;
  const size_t half = (size_t)64 * 768;

  for (int k0 = 0; k0 < 768; k0 += 32) {
    __syncthreads();
    gload16(ap + k0,        As + lb);
    gload16(ap + half + k0, As + 2048 + lb);
    gload16(bp + k0,        Bs + lb);
    gload16(bp + half + k0, Bs + 2048 + lb);
    __syncthreads();
    bf16x8 af[4], bfr[4];
    #pragma unroll
    for (int i = 0; i < 4; ++i)
      af[i] = *(const bf16x8*)&As[(wr + i * 16 + llo) * 32 + lhi * 8];
    #pragma unroll
    for (int n = 0; n < 4; ++n)
      bfr[n] = *(const bf16x8*)&Bs[(wc + n * 16 + llo) * 32 + lhi * 8];
    #pragma unroll
    for (int i = 0; i < 4; ++i)
      #pragma unroll
      for (int n = 0; n < 4; ++n)
        MFMA16(acc[i][n], af[i], bfr[n]);
  }

  #pragma unroll
  for (int i = 0; i < 4; ++i)
    #pragma unroll
    for (int n = 0; n < 4; ++n) {
      const int gc = n0 + wc + n * 16 + llo;
      const float bb = bias[gc];
      #pragma unroll
      for (int r = 0; r < 4; ++r) {
        const int row = m0 + wr + i * 16 + lhi * 4 + r;
        Out[(size_t)row * 768 + gc] = acc[i][n][r] + bb;
      }
    }
}

// ---------------------------------------------------------------------------
extern "C" void kernel_launch(void* const* d_in, const int* in_sizes, int n_in,
                              void* d_out, int out_size, void* d_ws, size_t ws_size,
                              hipStream_t stream) {
  const float* x    = (const float*)d_in[0];
  const float* Wqkv = (const float*)d_in[1];
  const float* Wo   = (const float*)d_in[2];
  const float* bo   = (const float*)d_in[3];
  float* out = (float*)d_out;

  const size_t SEG = (size_t)48 * 2048 * 64;  // 6291456
  float* qf  = (float*)d_ws;                  // [SEG] fp32
  u16* kk    = (u16*)(qf + SEG);              // [SEG]
  u16* vt    = kk + SEG;                      // [SEG]
  u16* xh    = vt + SEG;                      // [SEG]  (becomes AO)
  u16* xl    = xh + SEG;                      // [SEG]
  u16* wth   = xl + SEG;                      // [2304*768]
  u16* wtl   = wth + (size_t)2304 * 768;
  u16* wot   = wtl + (size_t)2304 * 768;      // [768*768]
  u16* ao    = xh;                            // alias: Xh dead after qkv_gemm

  prep_x_kernel <<<dim3(6144), 256, 0, stream>>>(x, xh, xl);
  prep_w_kernel <<<dim3(24, 72), 256, 0, stream>>>(Wqkv, wth, wtl, 768, 2304);
  prep_wo_kernel<<<dim3(24, 24), 256, 0, stream>>>(Wo, wot, 768, 768);
  qkv_gemm_kernel<<<dim3(64, 18), 256, 0, stream>>>(xh, xl, wth, wtl, qf, kk, vt);
  attn_kernel   <<<dim3(16, 48), 256, 0, stream>>>(qf, kk, vt, ao);
  out_gemm_kernel<<<dim3(64, 6), 256, 0, stream>>>(ao, wot, bo, out);
}